// Round 9
// baseline (91.554 us; speedup 1.0000x reference)
//
#include <hip/hip_runtime.h>
#include <math.h>

#define BLOCK 256
#define NBLOCKS 2048
#define UNROLL 4
#define EPS 1e-10f
#define LAMBD 0.5f

// Native clang vector type — maps to a 4-VGPR tuple for asm "v" constraints.
typedef float vf4 __attribute__((ext_vector_type(4)));

// Inline-asm loads: forces all 8 to issue back-to-back (volatile asm keeps
// program order among themselves; the compiler provably refuses to batch
// plain loads here — VGPR=24..36 across R2-R8 with ~2 in flight).
//   outputs: cached (L3-resident across replays, R8 FETCH evidence)
//   labels:  nt (evict-first stream, doesn't displace outputs in L3)
#define LOAD_C(dst, ptr)                                                   \
    asm volatile("global_load_dwordx4 %0, %1, off" : "=v"(dst) : "v"(ptr))
#define LOAD_NT(dst, ptr)                                                  \
    asm volatile("global_load_dwordx4 %0, %1, off nt" : "=v"(dst) : "v"(ptr))

// Per-element accumulate: sse += (o-l)^2, sl += l, tp += l*(o>0.5)
#define ACC(o, l)                                                         \
    do {                                                                  \
        float d0 = o.x - l.x, d1 = o.y - l.y;                             \
        float d2 = o.z - l.z, d3 = o.w - l.w;                             \
        sse += d0 * d0 + d1 * d1 + d2 * d2 + d3 * d3;                     \
        sl  += l.x + l.y + l.z + l.w;                                     \
        tp  += (o.x > 0.5f ? l.x : 0.f) + (o.y > 0.5f ? l.y : 0.f)        \
             + (o.z > 0.5f ? l.z : 0.f) + (o.w > 0.5f ? l.w : 0.f);       \
    } while (0)

__global__ __launch_bounds__(BLOCK, 4) void detloss_reduce(
    const vf4* __restrict__ o4, const vf4* __restrict__ l4,
    float* __restrict__ part, int n4, long long n,
    const float* __restrict__ outp, const float* __restrict__ lab) {

    float sse = 0.f, tp = 0.f, sl = 0.f;

    const int stride = gridDim.x * BLOCK;          // float4 units
    const int chunk  = stride * UNROLL;
    const int n_main = (n4 / chunk) * chunk;

    int i = blockIdx.x * BLOCK + threadIdx.x;

    for (; i < n_main; i += chunk) {
        vf4 o0, o1, o2, o3, l0, l1, l2, l3;
        // 8 loads in flight (MLP=8) before any wait.
        LOAD_C (o0, &o4[i             ]);
        LOAD_NT(l0, &l4[i             ]);
        LOAD_C (o1, &o4[i +     stride]);
        LOAD_NT(l1, &l4[i +     stride]);
        LOAD_C (o2, &o4[i + 2 * stride]);
        LOAD_NT(l2, &l4[i + 2 * stride]);
        LOAD_C (o3, &o4[i + 3 * stride]);
        LOAD_NT(l3, &l4[i + 3 * stride]);
        asm volatile("s_waitcnt vmcnt(0)" ::: "memory");
        __builtin_amdgcn_sched_barrier(0);   // rule #18: pin consumers after wait
        ACC(o0, l0); ACC(o1, l1); ACC(o2, l2); ACC(o3, l3);
    }

    // Remainder float4s (grid-stride) — compiler-managed loads.
    for (; i < n4; i += stride) {
        vf4 o = o4[i];
        vf4 l = __builtin_nontemporal_load(&l4[i]);
        ACC(o, l);
    }

    // Scalar tail (n not divisible by 4) — thread 0 of block 0.
    if (blockIdx.x == 0 && threadIdx.x == 0) {
        for (long long j = (long long)n4 << 2; j < n; ++j) {
            float o = outp[j], l = lab[j];
            float d = o - l;
            sse += d * d;
            sl  += l;
            tp  += (o > 0.5f ? l : 0.f);
        }
    }

    // Wave-64 reduce.
    for (int off = 32; off > 0; off >>= 1) {
        sse += __shfl_down(sse, off);
        tp  += __shfl_down(tp,  off);
        sl  += __shfl_down(sl,  off);
    }

    __shared__ float s_sse[BLOCK / 64], s_tp[BLOCK / 64], s_sl[BLOCK / 64];
    const int lane = threadIdx.x & 63;
    const int wave = threadIdx.x >> 6;
    if (lane == 0) { s_sse[wave] = sse; s_tp[wave] = tp; s_sl[wave] = sl; }
    __syncthreads();

    if (threadIdx.x == 0) {
        float bsse = 0.f, btp = 0.f, bsl = 0.f;
        for (int w = 0; w < BLOCK / 64; ++w) {
            bsse += s_sse[w]; btp += s_tp[w]; bsl += s_sl[w];
        }
        const int nb = gridDim.x;
        part[blockIdx.x]          = bsse;
        part[nb + blockIdx.x]     = btp;
        part[2 * nb + blockIdx.x] = bsl;
    }
}

// Final: one 256-thread block reduces nblk x 3 partials + epilogue.
__global__ __launch_bounds__(256) void detloss_final(
    const float* __restrict__ part, int nblk,
    float* __restrict__ out, float inv_n) {

    float sse = 0.f, tp = 0.f, sl = 0.f;
    for (int i = threadIdx.x; i < nblk; i += 256) {
        sse += part[i];
        tp  += part[nblk + i];
        sl  += part[2 * nblk + i];
    }
    for (int off = 32; off > 0; off >>= 1) {
        sse += __shfl_down(sse, off);
        tp  += __shfl_down(tp,  off);
        sl  += __shfl_down(sl,  off);
    }
    __shared__ float s[3][4];
    const int lane = threadIdx.x & 63;
    const int wave = threadIdx.x >> 6;
    if (lane == 0) { s[0][wave] = sse; s[1][wave] = tp; s[2][wave] = sl; }
    __syncthreads();

    if (threadIdx.x == 0) {
        sse = s[0][0] + s[0][1] + s[0][2] + s[0][3];
        tp  = s[1][0] + s[1][1] + s[1][2] + s[1][3];
        sl  = s[2][0] + s[2][1] + s[2][2] + s[2][3];
        float fn = sl - tp;
        float coeff;
        if (tp == 0.f && fn == 0.f)      coeff = 1.f;
        else if (tp == 0.f)              coeff = 0.f;
        else                             coeff = tp / (tp + fn);
        float cost = -logf(coeff + EPS);
        out[0] = sse * inv_n + LAMBD * cost;
    }
}

extern "C" void kernel_launch(void* const* d_in, const int* in_sizes, int n_in,
                              void* d_out, int out_size, void* d_ws, size_t ws_size,
                              hipStream_t stream) {
    const float* outp = (const float*)d_in[0];
    const float* lab  = (const float*)d_in[1];
    float* out  = (float*)d_out;
    float* part = (float*)d_ws;   // 3 * NBLOCKS floats = 24 KB

    long long n = (long long)in_sizes[0];
    int n4 = (int)(n >> 2);

    int blocks = (n4 + BLOCK - 1) / BLOCK;
    if (blocks > NBLOCKS) blocks = NBLOCKS;
    if (blocks < 1) blocks = 1;

    detloss_reduce<<<blocks, BLOCK, 0, stream>>>(
        (const vf4*)outp, (const vf4*)lab, part, n4, n, outp, lab);
    detloss_final<<<1, 256, 0, stream>>>(part, blocks, out, 1.0f / (float)n);
}